// Round 1
// baseline (2621.339 us; speedup 1.0000x reference)
//
#include <hip/hip_runtime.h>
#include <math.h>

typedef float f4 __attribute__((ext_vector_type(4)));

#define THREADS 512
#define HID 256
#define SMP 32   // samples per block (8 waves x 4 samples)
#define CH 16    // weight k-rows staged per LDS chunk (16x256 fp32 = 16 KB)

// ---------------- prep: transpose weights into ws ----------------
// ws layout (floats): [0]=W1T 256x256 (W1T[k][n]=W1[n][k]),
//   [65536]=W2T 256x256, [131072]=WoutT 32x256 (WoutT[j][k]=Wout[k][j])
__global__ void k_prep(const float* __restrict__ W1, const float* __restrict__ W2,
                       const float* __restrict__ Wout, float* __restrict__ ws) {
  float* W1T = ws;
  float* W2T = ws + 65536;
  float* WoutT = ws + 131072;
  int tid = blockIdx.x * 256 + threadIdx.x;
  if (tid < 65536) {
    int k = tid >> 8, n = tid & 255;
    W1T[tid] = W1[n * 256 + k];
    W2T[tid] = W2[n * 256 + k];
    if (tid < 8192) {
      int k2 = tid >> 8, n2 = tid & 255;   // WoutT[32][256]
      WoutT[tid] = Wout[n2 * 32 + k2];
    }
  }
}

// softplus = np fp32 semantics (DO NOT TOUCH — mask-critical):
//   sp = max(z,0) + log1pf(expf(-|z|)), each libm call correctly rounded
//   via double intermediates. Verified bit-faithful in rounds 6-8.
__device__ __forceinline__ float sp_cr(float z) {
  float az = fabsf(z);
  float e  = (float)exp(-(double)az);
  float lp = (float)log1p((double)e);
  return fmaxf(z, 0.0f) + lp;
}

// backward factor: sigmoid(z) = 1 - exp(-softplus(z)) from stored activation.
__device__ __forceinline__ float sig_from_h(float h) {
  return 1.0f - __expf(-h);
}

// ---- forward chunk MAC, S=4 samples: exact np per-element order
// ---- (ascending k, mul-then-add, single accumulator per (s,col)).
__device__ __forceinline__ void mac_fwd4(const float* __restrict__ h0r,
                                         const float* __restrict__ h1r,
                                         const float* __restrict__ h2r,
                                         const float* __restrict__ h3r,
                                         const float* __restrict__ wl,
                                         int l, f4& a0, f4& a1, f4& a2, f4& a3) {
#pragma clang fp contract(off)
  #pragma unroll
  for (int k = 0; k < CH; k += 4) {
    f4 x0 = *(const f4*)&h0r[k];
    f4 x1 = *(const f4*)&h1r[k];
    f4 x2 = *(const f4*)&h2r[k];
    f4 x3 = *(const f4*)&h3r[k];
    #pragma unroll
    for (int kk = 0; kk < 4; ++kk) {
      f4 wv = *(const f4*)&wl[(k + kk) * 256 + l * 4];
      #pragma unroll
      for (int m = 0; m < 4; ++m) { float p = x0[kk] * wv[m]; a0[m] = a0[m] + p; }
      #pragma unroll
      for (int m = 0; m < 4; ++m) { float p = x1[kk] * wv[m]; a1[m] = a1[m] + p; }
      #pragma unroll
      for (int m = 0; m < 4; ++m) { float p = x2[kk] * wv[m]; a2[m] = a2[m] + p; }
      #pragma unroll
      for (int m = 0; m < 4; ++m) { float p = x3[kk] * wv[m]; a3[m] = a3[m] + p; }
    }
  }
}

// backward chunk MAC, S=4 (smooth path, FMA ok — same per-sample order as before)
__device__ __forceinline__ void mac_bwd4(const float* __restrict__ h0r,
                                         const float* __restrict__ h1r,
                                         const float* __restrict__ h2r,
                                         const float* __restrict__ h3r,
                                         const float* __restrict__ wl,
                                         int l, f4& a0, f4& a1, f4& a2, f4& a3) {
  #pragma unroll
  for (int k = 0; k < CH; k += 4) {
    f4 x0 = *(const f4*)&h0r[k];
    f4 x1 = *(const f4*)&h1r[k];
    f4 x2 = *(const f4*)&h2r[k];
    f4 x3 = *(const f4*)&h3r[k];
    #pragma unroll
    for (int kk = 0; kk < 4; ++kk) {
      f4 wv = *(const f4*)&wl[(k + kk) * 256 + l * 4];
      #pragma unroll
      for (int m = 0; m < 4; ++m) a0[m] = fmaf(x0[kk], wv[m], a0[m]);
      #pragma unroll
      for (int m = 0; m < 4; ++m) a1[m] = fmaf(x1[kk], wv[m], a1[m]);
      #pragma unroll
      for (int m = 0; m < 4; ++m) a2[m] = fmaf(x2[kk], wv[m], a2[m]);
      #pragma unroll
      for (int m = 0; m < 4; ++m) a3[m] = fmaf(x3[kk], wv[m], a3[m]);
    }
  }
}

// staged K-loop layer with register-prefetch software pipeline:
//   barrier; ds_write(chunk c); barrier; global_load(chunk c+1)->regs; mac(c)
// The prefetch loads stay in flight under the mac VALU phase (T14 split).
template <int K, bool FWD>
__device__ __forceinline__ void staged_layer(
    const float* __restrict__ Wbase,      // [K][256] row-major
    const float* __restrict__ hin,        // base of [SMP][K]
    int sA, int l, int tid, f4* wbuf4, const float* wl,
    f4& a0, f4& a1, f4& a2, f4& a3) {
  a0 = (f4){0, 0, 0, 0}; a1 = a0; a2 = a0; a3 = a0;
  const f4* src = (const f4*)Wbase;
  f4 r0 = src[tid];
  f4 r1 = src[tid + THREADS];
  constexpr int NC = K / CH;
  #pragma unroll 1
  for (int c = 0; c < NC; ++c) {
    __syncthreads();                       // prev chunk readers / prev layer done
    wbuf4[tid] = r0;
    wbuf4[tid + THREADS] = r1;
    __syncthreads();
    if (c + 1 < NC) {
      const f4* s2 = (const f4*)(Wbase + (size_t)(c + 1) * CH * 256);
      r0 = s2[tid];
      r1 = s2[tid + THREADS];
    }
    const float* h0 = hin + (size_t)(sA + 0) * K + c * CH;
    const float* h1 = hin + (size_t)(sA + 1) * K + c * CH;
    const float* h2 = hin + (size_t)(sA + 2) * K + c * CH;
    const float* h3 = hin + (size_t)(sA + 3) * K + c * CH;
    if constexpr (FWD) mac_fwd4(h0, h1, h2, h3, wl, l, a0, a1, a2, a3);
    else               mac_bwd4(h0, h1, h2, h3, wl, l, a0, a1, a2, a3);
  }
}

__device__ __forceinline__ void sp_store(f4 a, const float* __restrict__ b,
                                         float* __restrict__ dstrow, int l) {
  f4 bv = *(const f4*)&b[l * 4];
  f4 o;
  #pragma unroll
  for (int m = 0; m < 4; ++m) o[m] = sp_cr(a[m] + bv[m]);
  *(f4*)&dstrow[l * 4] = o;
}

__device__ __forceinline__ void sig_store(f4 a, float* __restrict__ hrow, int l) {
  f4 h = *(f4*)&hrow[l * 4];
  #pragma unroll
  for (int m = 0; m < 4; ++m) h[m] = a[m] * sig_from_h(h[m]);
  *(f4*)&hrow[l * 4] = h;
}

// ---------------- fused MLP fwd (np-faithful) + bwd + c = dvdx@G ------------
// R9 lane mapping: wave w owns samples w*4..w*4+3 (S=4 register blocking —
// each staged weight f4 now feeds 4 samples instead of 2: 1.5x LDS-read cut
// on the big layers, which are LDS-throughput bound per rocprof). lane l owns
// cols l*4..l*4+3. 120 KB LDS -> 1 block/CU, grid halves -> weight re-stream
// (FETCH_SIZE) halves too.
__global__ __launch_bounds__(THREADS, 2) void k_main(
    const float* __restrict__ x,
    const float* __restrict__ W0, const float* __restrict__ b0,
    const float* __restrict__ W1, const float* __restrict__ b1,
    const float* __restrict__ W2, const float* __restrict__ b2,
    const float* __restrict__ Wout, const float* __restrict__ bout,
    const float* __restrict__ G, const float* __restrict__ ws,
    float* __restrict__ out) {
  __shared__ float xs[SMP][32];       // 4 KB
  __shared__ float ha[SMP][HID];      // 32 KB : h0, then dz0
  __shared__ float hb[SMP][HID];      // 32 KB : h1, then dz1
  __shared__ float hc[SMP][HID];      // 32 KB : h2, then dz2
  __shared__ float zm[SMP][32];       // 4 KB  : mask, then dvdx
  __shared__ f4 wbuf4[CH * 64];       // 16 KB : staged weight chunk
  float* wl = (float*)wbuf4;

  const float* W1T = ws;
  const float* W2T = ws + 65536;
  const float* WoutT = ws + 131072;

  const int tid = threadIdx.x;
  const int w = tid >> 6;             // wave 0..7 -> samples w*4 .. w*4+3
  const int l = tid & 63;             // cols l*4..l*4+3
  const int sA = w * 4;
  const int s0 = blockIdx.x * SMP;

  for (int i = tid; i < SMP * 32; i += THREADS) {
    xs[i >> 5][i & 31] = x[(size_t)s0 * 32 + i];
  }

  // ---- L0: h0 = softplus(xs @ W0 + b0) -> ha  (K=32) ----
  {
    f4 a0, a1, a2, a3;
    staged_layer<32, true>(W0, &xs[0][0], sA, l, tid, wbuf4, wl, a0, a1, a2, a3);
    sp_store(a0, b0, &ha[sA + 0][0], l);
    sp_store(a1, b0, &ha[sA + 1][0], l);
    sp_store(a2, b0, &ha[sA + 2][0], l);
    sp_store(a3, b0, &ha[sA + 3][0], l);
  }

  // ---- L1: h1 = softplus(h0 @ W1 + b1) -> hb  (K=256) ----
  {
    f4 a0, a1, a2, a3;
    staged_layer<256, true>(W1, &ha[0][0], sA, l, tid, wbuf4, wl, a0, a1, a2, a3);
    sp_store(a0, b1, &hb[sA + 0][0], l);
    sp_store(a1, b1, &hb[sA + 1][0], l);
    sp_store(a2, b1, &hb[sA + 2][0], l);
    sp_store(a3, b1, &hb[sA + 3][0], l);
  }

  // ---- L2: h2 = softplus(h1 @ W2 + b2) -> hc ----
  {
    f4 a0, a1, a2, a3;
    staged_layer<256, true>(W2, &hb[0][0], sA, l, tid, wbuf4, wl, a0, a1, a2, a3);
    sp_store(a0, b2, &hc[sA + 0][0], l);
    sp_store(a1, b2, &hc[sA + 1][0], l);
    sp_store(a2, b2, &hc[sA + 2][0], l);
    sp_store(a3, b2, &hc[sA + 3][0], l);
  }
  __syncthreads();

  // ---- L3: z3 = h2 @ Wout + bout ; mask -> zm (exact np order; WoutT rows,
  // ---- 32 KB/block, L1-resident — unstaged). 1024 (s,j) pairs -> 2 reps. ----
  {
#pragma clang fp contract(off)
    #pragma unroll
    for (int rep = 0; rep < 2; ++rep) {
      int idx = tid + rep * THREADS;
      int s = idx >> 5, j = idx & 31;
      const float* wrow = WoutT + (size_t)j * 256;   // WoutT[j][k] = Wout[k][j]
      float acc = 0.0f;
      #pragma unroll 4
      for (int k = 0; k < 256; k += 4) {
        f4 hv = *(const f4*)&hc[s][k];
        f4 wv = *(const f4*)&wrow[k];
        #pragma unroll
        for (int kk = 0; kk < 4; ++kk) {
          float p = hv[kk] * wv[kk];
          acc = acc + p;
        }
      }
      zm[s][j] = (acc + bout[j] > 0.0f) ? 1.0f : 0.0f;
    }
  }

  // ---- B2: dz2 = (mask @ WoutT) * sig(h2) -> hc in-place (K=32) ----
  {
    f4 a0, a1, a2, a3;
    staged_layer<32, false>(WoutT, &zm[0][0], sA, l, tid, wbuf4, wl, a0, a1, a2, a3);
    sig_store(a0, &hc[sA + 0][0], l);
    sig_store(a1, &hc[sA + 1][0], l);
    sig_store(a2, &hc[sA + 2][0], l);
    sig_store(a3, &hc[sA + 3][0], l);
  }

  // ---- B1: dz1 = (dz2 @ W2T) * sig(h1) -> hb in-place ----
  {
    f4 a0, a1, a2, a3;
    staged_layer<256, false>(W2T, &hc[0][0], sA, l, tid, wbuf4, wl, a0, a1, a2, a3);
    sig_store(a0, &hb[sA + 0][0], l);
    sig_store(a1, &hb[sA + 1][0], l);
    sig_store(a2, &hb[sA + 2][0], l);
    sig_store(a3, &hb[sA + 3][0], l);
  }

  // ---- B0: dz0 = (dz1 @ W1T) * sig(h0) -> ha in-place ----
  {
    f4 a0, a1, a2, a3;
    staged_layer<256, false>(W1T, &hb[0][0], sA, l, tid, wbuf4, wl, a0, a1, a2, a3);
    sig_store(a0, &ha[sA + 0][0], l);
    sig_store(a1, &ha[sA + 1][0], l);
    sig_store(a2, &ha[sA + 2][0], l);
    sig_store(a3, &ha[sA + 3][0], l);
  }
  __syncthreads();

  // ---- BX: dvdx = dz0 @ W0T -> zm (W0 rows, 32 KB/block, unstaged) ----
  {
    #pragma unroll
    for (int rep = 0; rep < 2; ++rep) {
      int idx = tid + rep * THREADS;
      int s = idx >> 5, j = idx & 31;
      const float* wrow = W0 + (size_t)j * 256;      // W0[j][k]
      float acc = 0.0f;
      #pragma unroll 4
      for (int k = 0; k < 256; k += 4) {
        f4 hv = *(const f4*)&ha[s][k];
        f4 wv = *(const f4*)&wrow[k];
        #pragma unroll
        for (int kk = 0; kk < 4; ++kk) {
          acc = fmaf(hv[kk], wv[kk], acc);
        }
      }
      zm[s][j] = acc;
    }
  }
  __syncthreads();

  // ---- C: c = dvdx @ G -> out ----
  if (tid < SMP * 8) {
    int s = tid >> 3, a = tid & 7;
    float acc = 0.0f;
    #pragma unroll
    for (int j = 0; j < 32; ++j) acc = fmaf(zm[s][j], G[j * 8 + a], acc);
    out[(size_t)(s0 + s) * 8 + a] = acc;
  }
}

// ---------------- BoxCDQP: in-place on d_out (c -> u) ----------------
__global__ __launch_bounds__(256) void k_qp(float* __restrict__ out,
                                            const float* __restrict__ R,
                                            const float* __restrict__ lower,
                                            const float* __restrict__ upper) {
  int t = blockIdx.x * 256 + threadIdx.x;
  float q[8][8], u[8], cc[8], lo[8], hi[8], dg[8];
  #pragma unroll
  for (int i = 0; i < 8; ++i) {
    lo[i] = lower[i];
    hi[i] = upper[i];
    u[i] = 0.0f;
    cc[i] = out[(size_t)t * 8 + i];
    #pragma unroll
    for (int j = 0; j < 8; ++j) q[i][j] = 2.0f * R[i * 8 + j];
  }
  #pragma unroll
  for (int i = 0; i < 8; ++i) dg[i] = q[i][i];

  #pragma unroll 1
  for (int it = 0; it < 30; ++it) {
    #pragma unroll
    for (int i = 0; i < 8; ++i) {
      float g = cc[i];
      #pragma unroll
      for (int j = 0; j < 8; ++j) g = fmaf(q[i][j], u[j], g);
      float v = u[i] - g / dg[i];
      u[i] = fminf(fmaxf(v, lo[i]), hi[i]);
    }
  }
  #pragma unroll
  for (int i = 0; i < 8; ++i) out[(size_t)t * 8 + i] = u[i];
}

extern "C" void kernel_launch(void* const* d_in, const int* in_sizes, int n_in,
                              void* d_out, int out_size, void* d_ws, size_t ws_size,
                              hipStream_t stream) {
  const float* x    = (const float*)d_in[0];
  // d_in[1] = t (unused)
  const float* W0   = (const float*)d_in[2];
  const float* b0   = (const float*)d_in[3];
  const float* W1   = (const float*)d_in[4];
  const float* b1   = (const float*)d_in[5];
  const float* W2   = (const float*)d_in[6];
  const float* b2   = (const float*)d_in[7];
  const float* Wout = (const float*)d_in[8];
  const float* bout = (const float*)d_in[9];
  const float* G    = (const float*)d_in[10];
  const float* R    = (const float*)d_in[11];
  const float* lower= (const float*)d_in[12];
  const float* upper= (const float*)d_in[13];
  float* out = (float*)d_out;
  float* ws  = (float*)d_ws;

  const int B = in_sizes[0] / 32;   // 131072

  k_prep<<<256, 256, 0, stream>>>(W1, W2, Wout, ws);
  k_main<<<B / SMP, THREADS, 0, stream>>>(x, W0, b0, W1, b1, W2, b2,
                                          Wout, bout, G, ws, out);
  k_qp<<<B / 256, 256, 0, stream>>>(out, R, lower, upper);
}

// Round 2
// 2011.395 us; speedup vs baseline: 1.3032x; 1.3032x over previous
//
#include <hip/hip_runtime.h>
#include <math.h>

typedef float f4 __attribute__((ext_vector_type(4)));

#define THREADS 256
#define HID 256
#define SMP 16   // samples per block (4 waves x 4 samples)
#define CH 16    // weight k-rows staged per LDS chunk (16x256 fp32 = 16 KB)

// ---------------- prep: transpose weights into ws ----------------
// ws layout (floats): [0]=W1T 256x256 (W1T[k][n]=W1[n][k]),
//   [65536]=W2T 256x256, [131072]=WoutT 32x256 (WoutT[j][k]=Wout[k][j])
__global__ void k_prep(const float* __restrict__ W1, const float* __restrict__ W2,
                       const float* __restrict__ Wout, float* __restrict__ ws) {
  float* W1T = ws;
  float* W2T = ws + 65536;
  float* WoutT = ws + 131072;
  int tid = blockIdx.x * 256 + threadIdx.x;
  if (tid < 65536) {
    int k = tid >> 8, n = tid & 255;
    W1T[tid] = W1[n * 256 + k];
    W2T[tid] = W2[n * 256 + k];
    if (tid < 8192) {
      int k2 = tid >> 8, n2 = tid & 255;   // WoutT[32][256]
      WoutT[tid] = Wout[n2 * 32 + k2];
    }
  }
}

// softplus = np fp32 semantics (DO NOT TOUCH — mask-critical):
//   sp = max(z,0) + log1pf(expf(-|z|)), each libm call correctly rounded
//   via double intermediates. Verified bit-faithful in rounds 6-8.
__device__ __forceinline__ float sp_cr(float z) {
  float az = fabsf(z);
  float e  = (float)exp(-(double)az);
  float lp = (float)log1p((double)e);
  return fmaxf(z, 0.0f) + lp;
}

// backward factor: sigmoid(z) = 1 - exp(-softplus(z)) from stored activation.
__device__ __forceinline__ float sig_from_h(float h) {
  return 1.0f - __expf(-h);
}

// ---- forward chunk MAC, S=4 samples: exact np per-element order
// ---- (ascending k, mul-then-add, single accumulator per (s,col)).
__device__ __forceinline__ void mac_fwd4(const float* __restrict__ h0r,
                                         const float* __restrict__ h1r,
                                         const float* __restrict__ h2r,
                                         const float* __restrict__ h3r,
                                         const float* __restrict__ wl,
                                         int l, f4& a0, f4& a1, f4& a2, f4& a3) {
#pragma clang fp contract(off)
  #pragma unroll
  for (int k = 0; k < CH; k += 4) {
    f4 x0 = *(const f4*)&h0r[k];
    f4 x1 = *(const f4*)&h1r[k];
    f4 x2 = *(const f4*)&h2r[k];
    f4 x3 = *(const f4*)&h3r[k];
    #pragma unroll
    for (int kk = 0; kk < 4; ++kk) {
      f4 wv = *(const f4*)&wl[(k + kk) * 256 + l * 4];
      #pragma unroll
      for (int m = 0; m < 4; ++m) { float p = x0[kk] * wv[m]; a0[m] = a0[m] + p; }
      #pragma unroll
      for (int m = 0; m < 4; ++m) { float p = x1[kk] * wv[m]; a1[m] = a1[m] + p; }
      #pragma unroll
      for (int m = 0; m < 4; ++m) { float p = x2[kk] * wv[m]; a2[m] = a2[m] + p; }
      #pragma unroll
      for (int m = 0; m < 4; ++m) { float p = x3[kk] * wv[m]; a3[m] = a3[m] + p; }
    }
  }
}

// backward chunk MAC, S=4 (smooth path, FMA ok — same per-sample order as before)
__device__ __forceinline__ void mac_bwd4(const float* __restrict__ h0r,
                                         const float* __restrict__ h1r,
                                         const float* __restrict__ h2r,
                                         const float* __restrict__ h3r,
                                         const float* __restrict__ wl,
                                         int l, f4& a0, f4& a1, f4& a2, f4& a3) {
  #pragma unroll
  for (int k = 0; k < CH; k += 4) {
    f4 x0 = *(const f4*)&h0r[k];
    f4 x1 = *(const f4*)&h1r[k];
    f4 x2 = *(const f4*)&h2r[k];
    f4 x3 = *(const f4*)&h3r[k];
    #pragma unroll
    for (int kk = 0; kk < 4; ++kk) {
      f4 wv = *(const f4*)&wl[(k + kk) * 256 + l * 4];
      #pragma unroll
      for (int m = 0; m < 4; ++m) a0[m] = fmaf(x0[kk], wv[m], a0[m]);
      #pragma unroll
      for (int m = 0; m < 4; ++m) a1[m] = fmaf(x1[kk], wv[m], a1[m]);
      #pragma unroll
      for (int m = 0; m < 4; ++m) a2[m] = fmaf(x2[kk], wv[m], a2[m]);
      #pragma unroll
      for (int m = 0; m < 4; ++m) a3[m] = fmaf(x3[kk], wv[m], a3[m]);
    }
  }
}

// staged K-loop layer with register-prefetch software pipeline:
//   barrier; ds_write(chunk c); barrier; global_load(chunk c+1)->regs; mac(c)
// The prefetch loads stay in flight under the mac VALU phase (T14 split).
// 256 threads stage 1024 f4 per chunk -> 4 f4 per thread.
template <int K, bool FWD>
__device__ __forceinline__ void staged_layer(
    const float* __restrict__ Wbase,      // [K][256] row-major
    const float* __restrict__ hin,        // base of [SMP][K]
    int sA, int l, int tid, f4* wbuf4, const float* wl,
    f4& a0, f4& a1, f4& a2, f4& a3) {
  a0 = (f4){0, 0, 0, 0}; a1 = a0; a2 = a0; a3 = a0;
  const f4* src = (const f4*)Wbase;
  f4 r0 = src[tid];
  f4 r1 = src[tid + THREADS];
  f4 r2 = src[tid + 2 * THREADS];
  f4 r3 = src[tid + 3 * THREADS];
  constexpr int NC = K / CH;
  #pragma unroll 1
  for (int c = 0; c < NC; ++c) {
    __syncthreads();                       // prev chunk readers / prev layer done
    wbuf4[tid] = r0;
    wbuf4[tid + THREADS] = r1;
    wbuf4[tid + 2 * THREADS] = r2;
    wbuf4[tid + 3 * THREADS] = r3;
    __syncthreads();
    if (c + 1 < NC) {
      const f4* s2 = (const f4*)(Wbase + (size_t)(c + 1) * CH * 256);
      r0 = s2[tid];
      r1 = s2[tid + THREADS];
      r2 = s2[tid + 2 * THREADS];
      r3 = s2[tid + 3 * THREADS];
    }
    const float* h0 = hin + (size_t)(sA + 0) * K + c * CH;
    const float* h1 = hin + (size_t)(sA + 1) * K + c * CH;
    const float* h2 = hin + (size_t)(sA + 2) * K + c * CH;
    const float* h3 = hin + (size_t)(sA + 3) * K + c * CH;
    if constexpr (FWD) mac_fwd4(h0, h1, h2, h3, wl, l, a0, a1, a2, a3);
    else               mac_bwd4(h0, h1, h2, h3, wl, l, a0, a1, a2, a3);
  }
}

__device__ __forceinline__ void sp_store(f4 a, const float* __restrict__ b,
                                         float* __restrict__ dstrow, int l) {
  f4 bv = *(const f4*)&b[l * 4];
  f4 o;
  #pragma unroll
  for (int m = 0; m < 4; ++m) o[m] = sp_cr(a[m] + bv[m]);
  *(f4*)&dstrow[l * 4] = o;
}

__device__ __forceinline__ void sig_store(f4 a, float* __restrict__ hrow, int l) {
  f4 h = *(f4*)&hrow[l * 4];
  #pragma unroll
  for (int m = 0; m < 4; ++m) h[m] = a[m] * sig_from_h(h[m]);
  *(f4*)&hrow[l * 4] = h;
}

// ---------------- fused MLP fwd (np-faithful) + bwd + c = dvdx@G ------------
// R10: S=4 register blocking (R9's LDS-read cut) at 2 blocks/CU (R7's overlap).
// 4 waves/block, wave w owns samples w*4..w*4+3, lane l owns cols l*4..l*4+3.
// 68 KB LDS -> 2 async blocks/CU: one block's mac covers the other's
// staging+barrier drain (R9 at 120 KB/1 block lost this and regressed).
__global__ __launch_bounds__(THREADS, 2) void k_main(
    const float* __restrict__ x,
    const float* __restrict__ W0, const float* __restrict__ b0,
    const float* __restrict__ W1, const float* __restrict__ b1,
    const float* __restrict__ W2, const float* __restrict__ b2,
    const float* __restrict__ Wout, const float* __restrict__ bout,
    const float* __restrict__ G, const float* __restrict__ ws,
    float* __restrict__ out) {
  __shared__ float xs[SMP][32];       // 2 KB
  __shared__ float ha[SMP][HID];      // 16 KB : h0, then dz0
  __shared__ float hb[SMP][HID];      // 16 KB : h1, then dz1
  __shared__ float hc[SMP][HID];      // 16 KB : h2, then dz2
  __shared__ float zm[SMP][32];       // 2 KB  : mask, then dvdx
  __shared__ f4 wbuf4[CH * 64];       // 16 KB : staged weight chunk
  float* wl = (float*)wbuf4;

  const float* W1T = ws;
  const float* W2T = ws + 65536;
  const float* WoutT = ws + 131072;

  const int tid = threadIdx.x;
  const int w = tid >> 6;             // wave 0..3 -> samples w*4 .. w*4+3
  const int l = tid & 63;             // cols l*4..l*4+3
  const int sA = w * 4;
  const int s0 = blockIdx.x * SMP;

  for (int i = tid; i < SMP * 32; i += THREADS) {
    xs[i >> 5][i & 31] = x[(size_t)s0 * 32 + i];
  }

  // ---- L0: h0 = softplus(xs @ W0 + b0) -> ha  (K=32) ----
  {
    f4 a0, a1, a2, a3;
    staged_layer<32, true>(W0, &xs[0][0], sA, l, tid, wbuf4, wl, a0, a1, a2, a3);
    sp_store(a0, b0, &ha[sA + 0][0], l);
    sp_store(a1, b0, &ha[sA + 1][0], l);
    sp_store(a2, b0, &ha[sA + 2][0], l);
    sp_store(a3, b0, &ha[sA + 3][0], l);
  }

  // ---- L1: h1 = softplus(h0 @ W1 + b1) -> hb  (K=256) ----
  {
    f4 a0, a1, a2, a3;
    staged_layer<256, true>(W1, &ha[0][0], sA, l, tid, wbuf4, wl, a0, a1, a2, a3);
    sp_store(a0, b1, &hb[sA + 0][0], l);
    sp_store(a1, b1, &hb[sA + 1][0], l);
    sp_store(a2, b1, &hb[sA + 2][0], l);
    sp_store(a3, b1, &hb[sA + 3][0], l);
  }

  // ---- L2: h2 = softplus(h1 @ W2 + b2) -> hc ----
  {
    f4 a0, a1, a2, a3;
    staged_layer<256, true>(W2, &hb[0][0], sA, l, tid, wbuf4, wl, a0, a1, a2, a3);
    sp_store(a0, b2, &hc[sA + 0][0], l);
    sp_store(a1, b2, &hc[sA + 1][0], l);
    sp_store(a2, b2, &hc[sA + 2][0], l);
    sp_store(a3, b2, &hc[sA + 3][0], l);
  }
  __syncthreads();

  // ---- L3: z3 = h2 @ Wout + bout ; mask -> zm (exact np order; WoutT rows,
  // ---- 32 KB/block, L1/L2-resident — unstaged). 512 (s,j) pairs -> 2 reps. --
  {
#pragma clang fp contract(off)
    #pragma unroll
    for (int rep = 0; rep < 2; ++rep) {
      int idx = tid + rep * THREADS;
      int s = idx >> 5, j = idx & 31;
      const float* wrow = WoutT + (size_t)j * 256;   // WoutT[j][k] = Wout[k][j]
      float acc = 0.0f;
      #pragma unroll 4
      for (int k = 0; k < 256; k += 4) {
        f4 hv = *(const f4*)&hc[s][k];
        f4 wv = *(const f4*)&wrow[k];
        #pragma unroll
        for (int kk = 0; kk < 4; ++kk) {
          float p = hv[kk] * wv[kk];
          acc = acc + p;
        }
      }
      zm[s][j] = (acc + bout[j] > 0.0f) ? 1.0f : 0.0f;
    }
  }

  // ---- B2: dz2 = (mask @ WoutT) * sig(h2) -> hc in-place (K=32) ----
  {
    f4 a0, a1, a2, a3;
    staged_layer<32, false>(WoutT, &zm[0][0], sA, l, tid, wbuf4, wl, a0, a1, a2, a3);
    sig_store(a0, &hc[sA + 0][0], l);
    sig_store(a1, &hc[sA + 1][0], l);
    sig_store(a2, &hc[sA + 2][0], l);
    sig_store(a3, &hc[sA + 3][0], l);
  }

  // ---- B1: dz1 = (dz2 @ W2T) * sig(h1) -> hb in-place ----
  {
    f4 a0, a1, a2, a3;
    staged_layer<256, false>(W2T, &hc[0][0], sA, l, tid, wbuf4, wl, a0, a1, a2, a3);
    sig_store(a0, &hb[sA + 0][0], l);
    sig_store(a1, &hb[sA + 1][0], l);
    sig_store(a2, &hb[sA + 2][0], l);
    sig_store(a3, &hb[sA + 3][0], l);
  }

  // ---- B0: dz0 = (dz1 @ W1T) * sig(h0) -> ha in-place ----
  {
    f4 a0, a1, a2, a3;
    staged_layer<256, false>(W1T, &hb[0][0], sA, l, tid, wbuf4, wl, a0, a1, a2, a3);
    sig_store(a0, &ha[sA + 0][0], l);
    sig_store(a1, &ha[sA + 1][0], l);
    sig_store(a2, &ha[sA + 2][0], l);
    sig_store(a3, &ha[sA + 3][0], l);
  }
  __syncthreads();

  // ---- BX: dvdx = dz0 @ W0T -> zm (W0 rows, 32 KB/block, unstaged) ----
  {
    #pragma unroll
    for (int rep = 0; rep < 2; ++rep) {
      int idx = tid + rep * THREADS;
      int s = idx >> 5, j = idx & 31;
      const float* wrow = W0 + (size_t)j * 256;      // W0[j][k]
      float acc = 0.0f;
      #pragma unroll 4
      for (int k = 0; k < 256; k += 4) {
        f4 hv = *(const f4*)&ha[s][k];
        f4 wv = *(const f4*)&wrow[k];
        #pragma unroll
        for (int kk = 0; kk < 4; ++kk) {
          acc = fmaf(hv[kk], wv[kk], acc);
        }
      }
      zm[s][j] = acc;
    }
  }
  __syncthreads();

  // ---- C: c = dvdx @ G -> out ----
  if (tid < SMP * 8) {
    int s = tid >> 3, a = tid & 7;
    float acc = 0.0f;
    #pragma unroll
    for (int j = 0; j < 32; ++j) acc = fmaf(zm[s][j], G[j * 8 + a], acc);
    out[(size_t)(s0 + s) * 8 + a] = acc;
  }
}

// ---------------- BoxCDQP: in-place on d_out (c -> u) ----------------
__global__ __launch_bounds__(256) void k_qp(float* __restrict__ out,
                                            const float* __restrict__ R,
                                            const float* __restrict__ lower,
                                            const float* __restrict__ upper) {
  int t = blockIdx.x * 256 + threadIdx.x;
  float q[8][8], u[8], cc[8], lo[8], hi[8], dg[8];
  #pragma unroll
  for (int i = 0; i < 8; ++i) {
    lo[i] = lower[i];
    hi[i] = upper[i];
    u[i] = 0.0f;
    cc[i] = out[(size_t)t * 8 + i];
    #pragma unroll
    for (int j = 0; j < 8; ++j) q[i][j] = 2.0f * R[i * 8 + j];
  }
  #pragma unroll
  for (int i = 0; i < 8; ++i) dg[i] = q[i][i];

  #pragma unroll 1
  for (int it = 0; it < 30; ++it) {
    #pragma unroll
    for (int i = 0; i < 8; ++i) {
      float g = cc[i];
      #pragma unroll
      for (int j = 0; j < 8; ++j) g = fmaf(q[i][j], u[j], g);
      float v = u[i] - g / dg[i];
      u[i] = fminf(fmaxf(v, lo[i]), hi[i]);
    }
  }
  #pragma unroll
  for (int i = 0; i < 8; ++i) out[(size_t)t * 8 + i] = u[i];
}

extern "C" void kernel_launch(void* const* d_in, const int* in_sizes, int n_in,
                              void* d_out, int out_size, void* d_ws, size_t ws_size,
                              hipStream_t stream) {
  const float* x    = (const float*)d_in[0];
  // d_in[1] = t (unused)
  const float* W0   = (const float*)d_in[2];
  const float* b0   = (const float*)d_in[3];
  const float* W1   = (const float*)d_in[4];
  const float* b1   = (const float*)d_in[5];
  const float* W2   = (const float*)d_in[6];
  const float* b2   = (const float*)d_in[7];
  const float* Wout = (const float*)d_in[8];
  const float* bout = (const float*)d_in[9];
  const float* G    = (const float*)d_in[10];
  const float* R    = (const float*)d_in[11];
  const float* lower= (const float*)d_in[12];
  const float* upper= (const float*)d_in[13];
  float* out = (float*)d_out;
  float* ws  = (float*)d_ws;

  const int B = in_sizes[0] / 32;   // 131072

  k_prep<<<256, 256, 0, stream>>>(W1, W2, Wout, ws);
  k_main<<<B / SMP, THREADS, 0, stream>>>(x, W0, b0, W1, b1, W2, b2,
                                          Wout, bout, G, ws, out);
  k_qp<<<B / 256, 256, 0, stream>>>(out, R, lower, upper);
}